// Round 6
// baseline (303.759 us; speedup 1.0000x reference)
//
#include <hip/hip_runtime.h>
#include <math.h>
#include <utility>

// B=16, T=16, FDIM=64, ODIM=8, NQ=10, NA=4, LAYERS=2, DEGREE=3.
// ROUND 6: one block per b = 16 waves x 64 lanes; wave w owns column (b, a=w)
// of 1024 complex amps in registers (n = lane*16 + r; bits[3:0]=r in-thread,
// [9:4]=lane). Gates on bit<4: thread-local. bit>=4: cross-lane butterfly
// (xor1/2/8 -> DPP, xor16/32 -> permlane16/32_swap VALU, xor4 -> shfl).
//
// ALL cross-column coupling (the rank-1 pcphase mixes, from round 5's
// algebra: M_k = conj(e_k) I + (e_k - conj(e_k)) u0 u0^dag) happens in LDS
// with __syncthreads() -- no global partials, no agent-scope atomics, no
// L2 writeback/invalidate, no spin. Mend mix still deleted (unitary on the
// ancilla index; expvals trace over ancilla). Workspace unused.
//
// LDS reduction: R[4][512] float4 (32 KB). Step 0: waves 0-3 write their
// partial p=conj(u0[a])*col into slot w. Steps g=1..3: waves 4g..4g+3 RMW
// slot w-4g += p (exclusive owner per slot per step). Then every wave sums
// the 4 slots. All accesses lane-contiguous b128 -> conflict-free.

struct Gate { int ry; int tbit; int cbit; int pidx; };
struct GateTab { Gate g[40]; };

constexpr GateTab make_gates1() {
  GateTab tb{};
  int pos = 0, idx = 0;
  for (int i = 0; i < 10; ++i) { tb.g[pos] = Gate{1, 9 - i, -1, idx}; ++pos; ++idx; }
  for (int i = 9; i >= 0; --i) { tb.g[pos] = Gate{0, 9 - ((i + 1) % 10), 9 - i, idx}; ++pos; ++idx; }
  for (int i = 0; i < 10; ++i) { tb.g[pos] = Gate{1, 9 - i, -1, idx}; ++pos; ++idx; }
  for (int k = 0; k < 10; ++k) {
    int i = (k == 0) ? 9 : (k - 1);
    tb.g[pos] = Gate{0, 9 - ((i + 9) % 10), 9 - i, idx}; ++pos; ++idx;
  }
  return tb;
}
constexpr GateTab GTC = make_gates1();

__device__ __forceinline__ int insert_zero(int v, int p) {
  return ((v >> p) << (p + 1)) | (v & ((1 << p) - 1));
}
__device__ __forceinline__ float2 cmul(float2 A, float2 B) {
  return make_float2(A.x * B.x - A.y * B.y, A.x * B.y + A.y * B.x);
}
__device__ __forceinline__ float2 conj2(float2 A) { return make_float2(A.x, -A.y); }

// ---------------- cross-lane xor ----------------
// xor1 = quad_perm[1,0,3,2]=0xB1, xor2 = quad_perm[2,3,0,1]=0x4E,
// xor8 = row_ror:8 = 0x128 (within 16-lane rows, (l+8)%16 == l^8).
// xor16/32: permlaneN_swap with both operands = v gives, per lane, the set
// {v[l], v[l^N]} across its two results (whichever row-direction convention
// the HW uses) -> v[l^N] = r0 ^ r1 ^ v bit-exactly.
template<int XM>
__device__ __forceinline__ float lxor(float v) {
  if constexpr (XM == 1) {
    int r = __builtin_amdgcn_update_dpp(__float_as_int(v), __float_as_int(v),
                                        0xB1, 0xF, 0xF, true);
    return __int_as_float(r);
  } else if constexpr (XM == 2) {
    int r = __builtin_amdgcn_update_dpp(__float_as_int(v), __float_as_int(v),
                                        0x4E, 0xF, 0xF, true);
    return __int_as_float(r);
  } else if constexpr (XM == 8) {
    int r = __builtin_amdgcn_update_dpp(__float_as_int(v), __float_as_int(v),
                                        0x128, 0xF, 0xF, true);
    return __int_as_float(r);
  } else if constexpr (XM == 16) {
#if __has_builtin(__builtin_amdgcn_permlane16_swap)
    unsigned uv = __float_as_uint(v);
    auto r = __builtin_amdgcn_permlane16_swap(uv, uv, false, false);
    return __uint_as_float(r[0] ^ r[1] ^ uv);
#else
    return __shfl_xor(v, 16, 64);
#endif
  } else if constexpr (XM == 32) {
#if __has_builtin(__builtin_amdgcn_permlane32_swap)
    unsigned uv = __float_as_uint(v);
    auto r = __builtin_amdgcn_permlane32_swap(uv, uv, false, false);
    return __uint_as_float(r[0] ^ r[1] ^ uv);
#else
    return __shfl_xor(v, 32, 64);
#endif
  } else {
    return __shfl_xor(v, XM, 64);
  }
}

__device__ __forceinline__ float wave_sum(float v) {
  v += lxor<1>(v);
  v += lxor<2>(v);
  v += lxor<4>(v);
  v += lxor<8>(v);
  v += lxor<16>(v);
  v += lxor<32>(v);
  return v;
}

// ---------------- register/shuffle gate engine ----------------
template<int P>
__device__ __forceinline__ void ry_gate(float2 (&a)[16], float c, float s, int lane) {
  if constexpr (P < 4) {
    constexpr int m = 1 << P;
#pragma unroll
    for (int r0 = 0; r0 < 16; ++r0) {
      if (!(r0 & m)) {
        int r1 = r0 | m;
        float2 a0 = a[r0], a1 = a[r1];
        a[r0] = make_float2(c * a0.x - s * a1.x, c * a0.y - s * a1.y);
        a[r1] = make_float2(s * a0.x + c * a1.x, s * a0.y + c * a1.y);
      }
    }
  } else {
    constexpr int xm = 1 << (P - 4);
    bool up = (lane >> (P - 4)) & 1;
    float sg = up ? s : -s;
#pragma unroll
    for (int r = 0; r < 16; ++r) {
      float wx = lxor<xm>(a[r].x);
      float wy = lxor<xm>(a[r].y);
      a[r].x = c * a[r].x + sg * wx;
      a[r].y = c * a[r].y + sg * wy;
    }
  }
}

template<int P, int Q>
__device__ __forceinline__ void crx_gate(float2 (&a)[16], float c, float s, int lane) {
  if constexpr (P < 4) {
    constexpr int m = 1 << P;
#pragma unroll
    for (int r0 = 0; r0 < 16; ++r0) {
      if (!(r0 & m)) {
        int r1 = r0 | m;
        bool act;
        if constexpr (Q < 4) act = (r0 >> Q) & 1;
        else act = (lane >> (Q - 4)) & 1;
        if (act) {
          float2 a0 = a[r0], a1 = a[r1];
          a[r0] = make_float2(c * a0.x + s * a1.y, c * a0.y - s * a1.x);
          a[r1] = make_float2(c * a1.x + s * a0.y, c * a1.y - s * a0.x);
        }
      }
    }
  } else {
    constexpr int xm = 1 << (P - 4);
#pragma unroll
    for (int r = 0; r < 16; ++r) {
      float wx = lxor<xm>(a[r].x);
      float wy = lxor<xm>(a[r].y);
      bool act;
      if constexpr (Q < 4) act = (r >> Q) & 1;
      else act = (lane >> (Q - 4)) & 1;
      if (act) {
        float nx = c * a[r].x + s * wy;
        float ny = c * a[r].y - s * wx;
        a[r].x = nx; a[r].y = ny;
      }
    }
  }
}

template<bool ADJ, int G>
__device__ __forceinline__ void one_gate(float2 (&a)[16], const float2* sc, int lane) {
  constexpr Gate g = GTC.g[ADJ ? (39 - G) : G];
  float2 scv = sc[g.pidx];            // LDS read, wave-uniform; TLP hides it
  float s = ADJ ? -scv.x : scv.x;
  float c = scv.y;
  if constexpr (g.ry != 0) ry_gate<g.tbit>(a, c, s, lane);
  else crx_gate<g.tbit, g.cbit>(a, c, s, lane);
}

template<bool ADJ, int... I>
__device__ __forceinline__ void run_layer_impl(float2 (&a)[16], const float2* sc,
                                               int lane, std::integer_sequence<int, I...>) {
  (one_gate<ADJ, I>(a, sc, lane), ...);
}
template<bool ADJ>
__device__ __forceinline__ void run_layer(float2 (&a)[16], const float2* sc, int lane) {
  run_layer_impl<ADJ>(a, sc, lane, std::make_integer_sequence<int, 40>{});
}

// ---------------- the fused one-block-per-b kernel ----------------
__global__ __launch_bounds__(1024) void k_fused(const float* __restrict__ x,
                                                const float* __restrict__ W_fp,
                                                const float* __restrict__ b_fp,
                                                const float* __restrict__ prep,
                                                const float* __restrict__ sig,
                                                const float* __restrict__ qff,
                                                const float* __restrict__ W_out,
                                                const float* __restrict__ b_out,
                                                float* __restrict__ out) {
  int b = blockIdx.x;
  int tid = threadIdx.x;
  int w = tid >> 6;                 // wave id = ancilla column a
  int lane = tid & 63;

  __shared__ float  h[16][64];      // per-wave feature row (t = w)
  __shared__ float2 scs[16][80];    // per-wave ts (sin,cos)
  __shared__ float2 qscs[40];
  __shared__ float2 ps[32];         // prep (sin,cos of th/2)
  __shared__ float2 es[4];          // e^{i sig_k} = (cos, sin)
  __shared__ float2 u0s[16];        // u0 = (prepare)|0>_anc
  __shared__ float4 R[4][512];      // 32 KB reduction buffer (reused for obs)

  // ---- phase 0a: h row for (b, t=w); stage small tables ----
  {
    int f = lane, k = f >> 1;
    float div = expf(-(float)(2 * k) * (logf(10000.f) / 64.f));
    float ang = (float)w * div;
    float pe = (f & 1) ? cosf(ang) : sinf(ang);
    h[w][f] = x[(b * 64 + f) * 16 + w] + pe;
  }
  if (w == 0) {
    if (lane < 32) {
      float s, c;
      sincosf(0.5f * prep[lane], &s, &c);
      ps[lane] = make_float2(s, c);
    } else if (lane < 36) {
      float s, c;
      sincosf(sig[lane - 32], &s, &c);
      es[lane - 32] = make_float2(c, s);
    }
  } else if (w == 1) {
    if (lane < 40) {
      float s, c;
      sincosf(0.5f * qff[lane], &s, &c);
      qscs[lane] = make_float2(s, c);
    }
  }
  __syncthreads();

  // ---- phase 0b: wave 0 builds u0 (16 complex, register evolution) ----
  if (w == 0) {
    float2 v[16];
#pragma unroll
    for (int i = 0; i < 16; ++i) v[i] = make_float2(i == 0 ? 1.f : 0.f, 0.f);
    for (int ly = 0; ly < 4; ++ly) {
#pragma unroll
      for (int qi = 0; qi < 4; ++qi) {
        int p = 3 - qi;
        float2 rc = ps[ly * 8 + qi * 2 + 0];      // ry
        {
          float s = rc.x, c = rc.y;
#pragma unroll
          for (int m = 0; m < 8; ++m) {
            int a0 = insert_zero(m, p), a1 = a0 | (1 << p);
            float2 t0 = v[a0], t1 = v[a1];
            v[a0] = make_float2(c * t0.x - s * t1.x, c * t0.y - s * t1.y);
            v[a1] = make_float2(s * t0.x + c * t1.x, s * t0.y + c * t1.y);
          }
        }
        rc = ps[ly * 8 + qi * 2 + 1];             // rz
        {
          float s = rc.x, c = rc.y;
#pragma unroll
          for (int m = 0; m < 8; ++m) {
            int a0 = insert_zero(m, p), a1 = a0 | (1 << p);
            float2 t0 = v[a0], t1 = v[a1];
            v[a0] = make_float2(c * t0.x + s * t0.y, c * t0.y - s * t0.x);
            v[a1] = make_float2(c * t1.x - s * t1.y, c * t1.y + s * t1.x);
          }
        }
      }
#pragma unroll
      for (int i = 0; i < 3; ++i) {
        int pc = 3 - i, pt = 2 - i;
#pragma unroll
        for (int m = 0; m < 4; ++m) {
          int mm = insert_zero(m, pt);
          mm = insert_zero(mm, pc);
          int a0 = mm | (1 << pc), a1 = a0 | (1 << pt);
          float2 t0 = v[a0], t1 = v[a1];
          v[a0] = t1; v[a1] = t0;
        }
      }
    }
    if (lane == 0) {
#pragma unroll
      for (int i = 0; i < 16; ++i) u0s[i] = v[i];
    }
  }

  // ---- phase 0c: ts dot products -> scs[w] (own-wave LDS, no block sync) ----
  for (int j = lane; j < 80; j += 64) {
    float acc = b_fp[j];
    const float* wr = W_fp + j * 64;
#pragma unroll 8
    for (int f = 0; f < 64; ++f) acc += h[w][f] * wr[f];
    float sg = 1.f / (1.f + expf(-acc));
    float s, c;
    sincosf(sg * 3.14159265358979323846f, &s, &c);   // theta/2 = sigmoid*pi
    scs[w][j] = make_float2(s, c);
  }
  __syncthreads();                   // u0s visible

  float2 u0aa = u0s[w];
  float2 e0 = es[0], e1 = es[1], e2 = es[2];
  float2 m0  = cmul(u0aa, e0);                  // (U D0)[a][0] * e^{i sig0}
  float2 cu0 = conj2(u0aa);
  float2 ce1 = conj2(e1);
  float2 w1  = make_float2(-2.f * e1.y * u0aa.y, 2.f * e1.y * u0aa.x);
  float2 ce2 = conj2(e2);
  float2 w2  = make_float2(-2.f * e2.y * u0aa.y, 2.f * e2.y * u0aa.x);

  const float2* sc = &scs[w][0];
  float2 a[16];

  // ---- phase 1: init |0..0> column + select fwd ----
#pragma unroll
  for (int r = 0; r < 16; ++r) a[r] = make_float2(0.f, 0.f);
  if (lane == 0) a[0] = m0;
  run_layer<false>(a, sc, lane);
  run_layer<false>(a, sc + 40, lane);

  // ---- mix 1 (LDS rank-1): col <- ce1*col + w1 * sum_a conj(u0[a])*col_a ----
  {
    __syncthreads();                 // prior R readers done (no-op first time)
    if (w < 4) {
#pragma unroll
      for (int q = 0; q < 8; ++q) {
        float2 p0 = cmul(cu0, a[2 * q]);
        float2 p1 = cmul(cu0, a[2 * q + 1]);
        R[w][q * 64 + lane] = make_float4(p0.x, p0.y, p1.x, p1.y);
      }
    }
    __syncthreads();
    for (int g = 1; g < 4; ++g) {
      if (w >= 4 * g && w < 4 * g + 4) {
#pragma unroll
        for (int q = 0; q < 8; ++q) {
          float4 v = R[w - 4 * g][q * 64 + lane];
          float2 p0 = cmul(cu0, a[2 * q]);
          float2 p1 = cmul(cu0, a[2 * q + 1]);
          R[w - 4 * g][q * 64 + lane] =
              make_float4(v.x + p0.x, v.y + p0.y, v.z + p1.x, v.w + p1.y);
        }
      }
      __syncthreads();
    }
#pragma unroll
    for (int q = 0; q < 8; ++q) {
      float4 s0 = R[0][q * 64 + lane];
      float4 s1 = R[1][q * 64 + lane];
      float4 s2 = R[2][q * 64 + lane];
      float4 s3 = R[3][q * 64 + lane];
      float4 sq = make_float4(s0.x + s1.x + s2.x + s3.x, s0.y + s1.y + s2.y + s3.y,
                              s0.z + s1.z + s2.z + s3.z, s0.w + s1.w + s2.w + s3.w);
      float2 a0 = a[2 * q], a1 = a[2 * q + 1];
      a[2 * q] = make_float2(ce1.x * a0.x - ce1.y * a0.y + w1.x * sq.x - w1.y * sq.y,
                             ce1.x * a0.y + ce1.y * a0.x + w1.x * sq.y + w1.y * sq.x);
      a[2 * q + 1] = make_float2(ce1.x * a1.x - ce1.y * a1.y + w1.x * sq.z - w1.y * sq.w,
                                 ce1.x * a1.y + ce1.y * a1.x + w1.x * sq.w + w1.y * sq.z);
    }
  }

  // ---- phase 2: select adjoint ----
  run_layer<true>(a, sc + 40, lane);
  run_layer<true>(a, sc, lane);

  // ---- mix 2 ----
  {
    __syncthreads();                 // everyone done reading R from mix 1
    if (w < 4) {
#pragma unroll
      for (int q = 0; q < 8; ++q) {
        float2 p0 = cmul(cu0, a[2 * q]);
        float2 p1 = cmul(cu0, a[2 * q + 1]);
        R[w][q * 64 + lane] = make_float4(p0.x, p0.y, p1.x, p1.y);
      }
    }
    __syncthreads();
    for (int g = 1; g < 4; ++g) {
      if (w >= 4 * g && w < 4 * g + 4) {
#pragma unroll
        for (int q = 0; q < 8; ++q) {
          float4 v = R[w - 4 * g][q * 64 + lane];
          float2 p0 = cmul(cu0, a[2 * q]);
          float2 p1 = cmul(cu0, a[2 * q + 1]);
          R[w - 4 * g][q * 64 + lane] =
              make_float4(v.x + p0.x, v.y + p0.y, v.z + p1.x, v.w + p1.y);
        }
      }
      __syncthreads();
    }
#pragma unroll
    for (int q = 0; q < 8; ++q) {
      float4 s0 = R[0][q * 64 + lane];
      float4 s1 = R[1][q * 64 + lane];
      float4 s2 = R[2][q * 64 + lane];
      float4 s3 = R[3][q * 64 + lane];
      float4 sq = make_float4(s0.x + s1.x + s2.x + s3.x, s0.y + s1.y + s2.y + s3.y,
                              s0.z + s1.z + s2.z + s3.z, s0.w + s1.w + s2.w + s3.w);
      float2 a0 = a[2 * q], a1 = a[2 * q + 1];
      a[2 * q] = make_float2(ce2.x * a0.x - ce2.y * a0.y + w2.x * sq.x - w2.y * sq.y,
                             ce2.x * a0.y + ce2.y * a0.x + w2.x * sq.y + w2.y * sq.x);
      a[2 * q + 1] = make_float2(ce2.x * a1.x - ce2.y * a1.y + w2.x * sq.z - w2.y * sq.w,
                                 ce2.x * a1.y + ce2.y * a1.x + w2.x * sq.w + w2.y * sq.z);
    }
  }

  // ---- phase 3: select fwd + qff (Mend mix deleted: unitary on ancilla) ----
  run_layer<false>(a, sc, lane);
  run_layer<false>(a, sc + 40, lane);
  run_layer<false>(a, &qscs[0], lane);

  // ---- phase 4: expvals -> per-wave obs -> LDS -> wave-0 output ----
  {
    float obs[30];
#pragma unroll
    for (int p = 0; p <= 9; ++p) {
      int i = 9 - p;
      float cr = 0.f, ci = 0.f, zz = 0.f;
      if (p < 4) {
        int m = 1 << p;
#pragma unroll
        for (int r0 = 0; r0 < 16; ++r0) {
          if (!(r0 & m)) {
            float2 A0 = a[r0], A1 = a[r0 | m];
            cr += A0.x * A1.x + A0.y * A1.y;
            ci += A0.x * A1.y - A0.y * A1.x;
            zz += (A0.x * A0.x + A0.y * A0.y) - (A1.x * A1.x + A1.y * A1.y);
          }
        }
      } else {
        int xm = 1 << (p - 4);
        bool up = (lane >> (p - 4)) & 1;
#pragma unroll
        for (int r = 0; r < 16; ++r) {
          float wx = __shfl_xor(a[r].x, xm, 64);
          float wy = __shfl_xor(a[r].y, xm, 64);
          float n2 = a[r].x * a[r].x + a[r].y * a[r].y;
          if (!up) {
            cr += a[r].x * wx + a[r].y * wy;
            ci += a[r].x * wy - a[r].y * wx;
            zz += n2;
          } else {
            zz -= n2;
          }
        }
      }
      obs[i] = 2.f * cr;
      obs[10 + i] = 2.f * ci;
      obs[20 + i] = zz;
    }
#pragma unroll
    for (int j = 0; j < 30; ++j) obs[j] = wave_sum(obs[j]);

    float* Rf = (float*)R;
    __syncthreads();                 // everyone done reading R from mix 2
    if (lane == 0) {
#pragma unroll
      for (int j = 0; j < 30; ++j) Rf[w * 30 + j] = obs[j];
    }
    __syncthreads();
    if (w == 0) {
      if (lane < 30) {
        float sv = 0.f;
#pragma unroll
        for (int wv = 0; wv < 16; ++wv) sv += Rf[wv * 30 + lane];
        Rf[480 + lane] = sv;
      }
      // same wave: LDS writes above complete (program order + lgkmcnt)
      if (lane < 8) {
        float acc = b_out[lane];
#pragma unroll
        for (int j = 0; j < 30; ++j) acc += W_out[lane * 30 + j] * Rf[480 + j];
        out[b * 8 + lane] = acc;
      }
    }
  }
}

extern "C" void kernel_launch(void* const* d_in, const int* in_sizes, int n_in,
                              void* d_out, int out_size, void* d_ws, size_t ws_size,
                              hipStream_t stream) {
  const float* x     = (const float*)d_in[0];
  const float* W_fp  = (const float*)d_in[1];
  const float* b_fp  = (const float*)d_in[2];
  const float* prep  = (const float*)d_in[3];
  const float* sig   = (const float*)d_in[4];
  const float* qff   = (const float*)d_in[5];
  const float* W_out = (const float*)d_in[6];
  const float* b_out = (const float*)d_in[7];
  float* out = (float*)d_out;
  (void)d_ws; (void)ws_size; (void)in_sizes; (void)n_in; (void)out_size;

  k_fused<<<dim3(16), dim3(1024), 0, stream>>>(x, W_fp, b_fp, prep, sig, qff,
                                               W_out, b_out, out);
}

// Round 7
// 170.326 us; speedup vs baseline: 1.7834x; 1.7834x over previous
//
#include <hip/hip_runtime.h>
#include <math.h>
#include <utility>

// B=16, T=16, FDIM=64, ODIM=8, NQ=10, NA=4, LAYERS=2, DEGREE=3.
// ROUND 7: 4 blocks per b (grid 64), 4 waves per block (256 thr), wave owns
// column (b, a = sub*4 + w): 1024 complex amps in regs (n = lane*16 + r).
// 1 wave/SIMD -> 512 VGPR budget (launch_bounds(256,1)): NO spills (round-6
// lesson: 1024-thr block forced 64 VGPRs -> scratch -> 239us).
// Gates on bit<4: thread-local. bit>=4: xor1/2/8 DPP, xor16/32 permlane
// swap (VALU), xor4 shfl. Rank-1 pcphase mixes (round-5 algebra):
//   M_k = conj(e_k) I + (e_k - conj(e_k)) u0 u0^dag,  u0 = (prepare)|0>.
// Mix = LDS pre-reduction of the 4 in-block partials -> ONE 8KB block
// partial to global -> 16-wave group barrier (proven cnt/gen pattern) ->
// read own (LDS) + 3 remote (24KB) partials. Mend mix deleted (unitary on
// ancilla; expvals trace it out).
// Code size: k-loop shares ONE fwd run_layer body (k=0,2 and qff via nL=1)
// and ONE adj body (#pragma unroll 1) -> ~2 bodies vs round-5's 7 (I$).

struct Gate { int ry; int tbit; int cbit; int pidx; };
struct GateTab { Gate g[40]; };

constexpr GateTab make_gates1() {
  GateTab tb{};
  int pos = 0, idx = 0;
  for (int i = 0; i < 10; ++i) { tb.g[pos] = Gate{1, 9 - i, -1, idx}; ++pos; ++idx; }
  for (int i = 9; i >= 0; --i) { tb.g[pos] = Gate{0, 9 - ((i + 1) % 10), 9 - i, idx}; ++pos; ++idx; }
  for (int i = 0; i < 10; ++i) { tb.g[pos] = Gate{1, 9 - i, -1, idx}; ++pos; ++idx; }
  for (int k = 0; k < 10; ++k) {
    int i = (k == 0) ? 9 : (k - 1);
    tb.g[pos] = Gate{0, 9 - ((i + 9) % 10), 9 - i, idx}; ++pos; ++idx;
  }
  return tb;
}
constexpr GateTab GTC = make_gates1();

__device__ __forceinline__ int insert_zero(int v, int p) {
  return ((v >> p) << (p + 1)) | (v & ((1 << p) - 1));
}
__device__ __forceinline__ float2 cmul(float2 A, float2 B) {
  return make_float2(A.x * B.x - A.y * B.y, A.x * B.y + A.y * B.x);
}
__device__ __forceinline__ float2 conj2(float2 A) { return make_float2(A.x, -A.y); }

// ---------------- cross-lane xor (DPP / permlane / shfl) ----------------
template<int XM>
__device__ __forceinline__ float lxor(float v) {
  if constexpr (XM == 1) {
    int r = __builtin_amdgcn_update_dpp(__float_as_int(v), __float_as_int(v),
                                        0xB1, 0xF, 0xF, true);
    return __int_as_float(r);
  } else if constexpr (XM == 2) {
    int r = __builtin_amdgcn_update_dpp(__float_as_int(v), __float_as_int(v),
                                        0x4E, 0xF, 0xF, true);
    return __int_as_float(r);
  } else if constexpr (XM == 8) {
    int r = __builtin_amdgcn_update_dpp(__float_as_int(v), __float_as_int(v),
                                        0x128, 0xF, 0xF, true);
    return __int_as_float(r);
  } else if constexpr (XM == 16) {
#if __has_builtin(__builtin_amdgcn_permlane16_swap)
    unsigned uv = __float_as_uint(v);
    auto r = __builtin_amdgcn_permlane16_swap(uv, uv, false, false);
    return __uint_as_float(r[0] ^ r[1] ^ uv);
#else
    return __shfl_xor(v, 16, 64);
#endif
  } else if constexpr (XM == 32) {
#if __has_builtin(__builtin_amdgcn_permlane32_swap)
    unsigned uv = __float_as_uint(v);
    auto r = __builtin_amdgcn_permlane32_swap(uv, uv, false, false);
    return __uint_as_float(r[0] ^ r[1] ^ uv);
#else
    return __shfl_xor(v, 32, 64);
#endif
  } else {
    return __shfl_xor(v, XM, 64);
  }
}

__device__ __forceinline__ float wave_sum(float v) {
  v += lxor<1>(v);
  v += lxor<2>(v);
  v += lxor<4>(v);
  v += lxor<8>(v);
  v += lxor<16>(v);
  v += lxor<32>(v);
  return v;
}

// ---------------- per-b group barrier (16 wave-parties) ----------------
// Monotonic words, zero-init at module load, never reset (round 3-5 proven).
struct alignas(128) GBar {
  unsigned cnt;        // barrier wave-arrivals, monotonic
  unsigned gen;        // completed rounds, monotonic
  unsigned done;       // block completions, monotonic
  unsigned pad[29];
};
__device__ GBar g_gb[16];

__device__ __forceinline__ void group_barrier16(int b, int lane) {
  unsigned snap = __hip_atomic_load(&g_gb[b].gen, __ATOMIC_RELAXED, __HIP_MEMORY_SCOPE_AGENT);
  if (lane == 0) {
    unsigned old = __hip_atomic_fetch_add(&g_gb[b].cnt, 1u, __ATOMIC_ACQ_REL,
                                          __HIP_MEMORY_SCOPE_AGENT);
    if ((old & 15u) == 15u)
      __hip_atomic_store(&g_gb[b].gen, snap + 1u, __ATOMIC_RELEASE,
                         __HIP_MEMORY_SCOPE_AGENT);
  }
  while (__hip_atomic_load(&g_gb[b].gen, __ATOMIC_RELAXED, __HIP_MEMORY_SCOPE_AGENT) == snap)
    __builtin_amdgcn_s_sleep(1);
  (void)__hip_atomic_load(&g_gb[b].gen, __ATOMIC_ACQUIRE, __HIP_MEMORY_SCOPE_AGENT);
}

// ---------------- register/shuffle gate engine ----------------
template<int P>
__device__ __forceinline__ void ry_gate(float2 (&a)[16], float c, float s, int lane) {
  if constexpr (P < 4) {
    constexpr int m = 1 << P;
#pragma unroll
    for (int r0 = 0; r0 < 16; ++r0) {
      if (!(r0 & m)) {
        int r1 = r0 | m;
        float2 a0 = a[r0], a1 = a[r1];
        a[r0] = make_float2(c * a0.x - s * a1.x, c * a0.y - s * a1.y);
        a[r1] = make_float2(s * a0.x + c * a1.x, s * a0.y + c * a1.y);
      }
    }
  } else {
    constexpr int xm = 1 << (P - 4);
    bool up = (lane >> (P - 4)) & 1;
    float sg = up ? s : -s;
#pragma unroll
    for (int r = 0; r < 16; ++r) {
      float wx = lxor<xm>(a[r].x);
      float wy = lxor<xm>(a[r].y);
      a[r].x = c * a[r].x + sg * wx;
      a[r].y = c * a[r].y + sg * wy;
    }
  }
}

template<int P, int Q>
__device__ __forceinline__ void crx_gate(float2 (&a)[16], float c, float s, int lane) {
  if constexpr (P < 4) {
    constexpr int m = 1 << P;
#pragma unroll
    for (int r0 = 0; r0 < 16; ++r0) {
      if (!(r0 & m)) {
        int r1 = r0 | m;
        bool act;
        if constexpr (Q < 4) act = (r0 >> Q) & 1;
        else act = (lane >> (Q - 4)) & 1;
        if (act) {
          float2 a0 = a[r0], a1 = a[r1];
          a[r0] = make_float2(c * a0.x + s * a1.y, c * a0.y - s * a1.x);
          a[r1] = make_float2(c * a1.x + s * a0.y, c * a1.y - s * a0.x);
        }
      }
    }
  } else {
    constexpr int xm = 1 << (P - 4);
#pragma unroll
    for (int r = 0; r < 16; ++r) {
      float wx = lxor<xm>(a[r].x);
      float wy = lxor<xm>(a[r].y);
      bool act;
      if constexpr (Q < 4) act = (r >> Q) & 1;
      else act = (lane >> (Q - 4)) & 1;
      if (act) {
        float nx = c * a[r].x + s * wy;
        float ny = c * a[r].y - s * wx;
        a[r].x = nx; a[r].y = ny;
      }
    }
  }
}

template<bool ADJ, int G>
__device__ __forceinline__ void one_gate(float2 (&a)[16], const float2 (&sc)[40], int lane) {
  constexpr Gate g = GTC.g[ADJ ? (39 - G) : G];
  float2 scv = sc[g.pidx];            // constexpr index -> VGPR
  float s = ADJ ? -scv.x : scv.x;
  float c = scv.y;
  if constexpr (g.ry != 0) ry_gate<g.tbit>(a, c, s, lane);
  else crx_gate<g.tbit, g.cbit>(a, c, s, lane);
}

template<bool ADJ, int... I>
__device__ __forceinline__ void run_layer_impl(float2 (&a)[16], const float2 (&sc)[40],
                                               int lane, std::integer_sequence<int, I...>) {
  (one_gate<ADJ, I>(a, sc, lane), ...);
}

// Preload the 40-entry (sin,cos) table into registers, then run the 40 gates.
template<bool ADJ>
__device__ __forceinline__ void run_layer(float2 (&a)[16], const float2* sc, int lane) {
  float2 rsc[40];
#pragma unroll
  for (int i = 0; i < 40; ++i) rsc[i] = sc[i];
  run_layer_impl<ADJ>(a, rsc, lane, std::make_integer_sequence<int, 40>{});
}

// ---------------- the fused kernel ----------------
__global__ __launch_bounds__(256, 1) void k_fused(const float* __restrict__ x,
                                                  const float* __restrict__ W_fp,
                                                  const float* __restrict__ b_fp,
                                                  const float* __restrict__ prep,
                                                  const float* __restrict__ sig,
                                                  const float* __restrict__ qff,
                                                  const float* __restrict__ W_out,
                                                  const float* __restrict__ b_out,
                                                  float* __restrict__ out,
                                                  float4* __restrict__ part1,
                                                  float4* __restrict__ part2,
                                                  float* __restrict__ sv) {
  int blk = blockIdx.x;
  int b = blk >> 2, sub = blk & 3;
  int tid = threadIdx.x;
  int w = tid >> 6, lane = tid & 63;
  int aa = sub * 4 + w;               // this wave's ancilla column

  __shared__ __align__(16) float h[4][64];   // per-wave feature row (t = aa)
  __shared__ float2 scs[4][80];              // per-wave ts (sin,cos)
  __shared__ float2 qscs[40];
  __shared__ float2 ps[32];                  // prep (sin,cos of th/2)
  __shared__ float2 es[4];                   // e^{i sig_k} = (cos, sin)
  __shared__ float2 u0s[16];                 // u0 = (prepare)|0>_anc
  __shared__ float4 R[2][512];               // 16 KB 2-slot reduction buffer

  // sv zero (ordered before atomics via barrier release chain)
  if (sub == 0 && w == 0 && lane < 30) sv[b * 30 + lane] = 0.f;

  // ---- phase 0a: h row for (b, t=aa); stage small tables ----
  {
    int f = lane, k = f >> 1;
    float div = expf(-(float)(2 * k) * (logf(10000.f) / 64.f));
    float ang = (float)aa * div;
    float pe = (f & 1) ? cosf(ang) : sinf(ang);
    h[w][f] = x[(b * 64 + f) * 16 + aa] + pe;
  }
  if (w == 0) {
    if (lane < 32) {
      float s, c;
      sincosf(0.5f * prep[lane], &s, &c);
      ps[lane] = make_float2(s, c);
    } else if (lane < 36) {
      float s, c;
      sincosf(sig[lane - 32], &s, &c);
      es[lane - 32] = make_float2(c, s);
    }
  } else if (w == 1 && lane < 40) {
    float s, c;
    sincosf(0.5f * qff[lane], &s, &c);
    qscs[lane] = make_float2(s, c);
  }
  __syncthreads();

  // ---- phase 0b: wave 0 builds u0 (16 complex, register evolution) ----
  if (w == 0) {
    float2 v[16];
#pragma unroll
    for (int i = 0; i < 16; ++i) v[i] = make_float2(i == 0 ? 1.f : 0.f, 0.f);
    for (int ly = 0; ly < 4; ++ly) {
#pragma unroll
      for (int qi = 0; qi < 4; ++qi) {
        int p = 3 - qi;
        float2 rc = ps[ly * 8 + qi * 2 + 0];      // ry
        {
          float s = rc.x, c = rc.y;
#pragma unroll
          for (int m = 0; m < 8; ++m) {
            int a0 = insert_zero(m, p), a1 = a0 | (1 << p);
            float2 t0 = v[a0], t1 = v[a1];
            v[a0] = make_float2(c * t0.x - s * t1.x, c * t0.y - s * t1.y);
            v[a1] = make_float2(s * t0.x + c * t1.x, s * t0.y + c * t1.y);
          }
        }
        rc = ps[ly * 8 + qi * 2 + 1];             // rz
        {
          float s = rc.x, c = rc.y;
#pragma unroll
          for (int m = 0; m < 8; ++m) {
            int a0 = insert_zero(m, p), a1 = a0 | (1 << p);
            float2 t0 = v[a0], t1 = v[a1];
            v[a0] = make_float2(c * t0.x + s * t0.y, c * t0.y - s * t0.x);
            v[a1] = make_float2(c * t1.x - s * t1.y, c * t1.y + s * t1.x);
          }
        }
      }
#pragma unroll
      for (int i = 0; i < 3; ++i) {
        int pc = 3 - i, pt = 2 - i;
#pragma unroll
        for (int m = 0; m < 4; ++m) {
          int mm = insert_zero(m, pt);
          mm = insert_zero(mm, pc);
          int a0 = mm | (1 << pc), a1 = a0 | (1 << pt);
          float2 t0 = v[a0], t1 = v[a1];
          v[a0] = t1; v[a1] = t0;
        }
      }
    }
    if (lane == 0) {
#pragma unroll
      for (int i = 0; i < 16; ++i) u0s[i] = v[i];
    }
  }

  // ---- phase 0c: ts dot products for this wave's column (t = aa) ----
  {
    const float4* h4 = (const float4*)&h[w][0];
    for (int j = lane; j < 80; j += 64) {
      float acc = b_fp[j];
      const float4* w4 = (const float4*)(W_fp + j * 64);
#pragma unroll
      for (int k4 = 0; k4 < 16; ++k4) {
        float4 hh = h4[k4], ww = w4[k4];
        acc += hh.x * ww.x + hh.y * ww.y + hh.z * ww.z + hh.w * ww.w;
      }
      float sg = 1.f / (1.f + expf(-acc));
      float s, c;
      sincosf(sg * 3.14159265358979323846f, &s, &c);   // theta/2 = sigmoid*pi
      scs[w][j] = make_float2(s, c);
    }
  }
  __syncthreads();                     // u0s + scs visible

  float2 u0aa = u0s[aa];
  float2 e0 = es[0], e1 = es[1], e2 = es[2];
  float2 m0  = cmul(u0aa, e0);
  float2 cu0 = conj2(u0aa);
  float2 ceA = conj2(e1);
  float2 wA  = make_float2(-2.f * e1.y * u0aa.y, 2.f * e1.y * u0aa.x);
  float2 ceB = conj2(e2);
  float2 wB  = make_float2(-2.f * e2.y * u0aa.y, 2.f * e2.y * u0aa.x);

  const float2* sc = &scs[w][0];
  float2 a[16];
#pragma unroll
  for (int r = 0; r < 16; ++r) a[r] = make_float2(0.f, 0.f);
  if (lane == 0) a[0] = m0;

  // ---- main loop: k=0 fwd | k=1 mix1+adj | k=2 mix2+fwd | k=3 qff ----
  for (int k = 0; k < 4; ++k) {
    if (k == 1 || k == 2) {
      float2 ce = (k == 1) ? ceA : ceB;
      float2 wk = (k == 1) ? wA : wB;
      float4* part = (k == 1) ? part1 : part2;

      // in-block 4->1 reduction of p = cu0 * col into R[0]+R[1]
      __syncthreads();               // R free (prev readers done)
      if (w < 2) {
#pragma unroll
        for (int q = 0; q < 8; ++q) {
          float2 p0 = cmul(cu0, a[2 * q]);
          float2 p1 = cmul(cu0, a[2 * q + 1]);
          R[w][q * 64 + lane] = make_float4(p0.x, p0.y, p1.x, p1.y);
        }
      }
      __syncthreads();
      if (w >= 2) {
#pragma unroll
        for (int q = 0; q < 8; ++q) {
          float4 v = R[w - 2][q * 64 + lane];
          float2 p0 = cmul(cu0, a[2 * q]);
          float2 p1 = cmul(cu0, a[2 * q + 1]);
          R[w - 2][q * 64 + lane] =
              make_float4(v.x + p0.x, v.y + p0.y, v.z + p1.x, v.w + p1.y);
        }
      }
      __syncthreads();
      // block partial (R0+R1) -> global, 2 q-slices per wave, coalesced
#pragma unroll
      for (int qq = 0; qq < 2; ++qq) {
        int q = w * 2 + qq;
        float4 v0 = R[0][q * 64 + lane];
        float4 v1 = R[1][q * 64 + lane];
        part[(size_t)(b * 4 + sub) * 512 + q * 64 + lane] =
            make_float4(v0.x + v1.x, v0.y + v1.y, v0.z + v1.z, v0.w + v1.w);
      }
      group_barrier16(b, lane);      // release covers our stores; acquire for reads

      // s = own block partial (LDS) + 3 remote block partials (global)
      float4 s4[8];
#pragma unroll
      for (int q = 0; q < 8; ++q) {
        float4 v0 = R[0][q * 64 + lane];
        float4 v1 = R[1][q * 64 + lane];
        s4[q] = make_float4(v0.x + v1.x, v0.y + v1.y, v0.z + v1.z, v0.w + v1.w);
      }
      for (int o = 1; o < 4; ++o) {
        int so = (sub + o) & 3;
        const float4* pp = part + (size_t)(b * 4 + so) * 512 + lane;
#pragma unroll
        for (int q = 0; q < 8; ++q) {
          float4 v = pp[q * 64];
          s4[q].x += v.x; s4[q].y += v.y; s4[q].z += v.z; s4[q].w += v.w;
        }
      }
      // col <- ce*col + wk*s
#pragma unroll
      for (int q = 0; q < 8; ++q) {
        float2 a0 = a[2 * q], a1 = a[2 * q + 1];
        a[2 * q] = make_float2(ce.x * a0.x - ce.y * a0.y + wk.x * s4[q].x - wk.y * s4[q].y,
                               ce.x * a0.y + ce.y * a0.x + wk.x * s4[q].y + wk.y * s4[q].x);
        a[2 * q + 1] = make_float2(ce.x * a1.x - ce.y * a1.y + wk.x * s4[q].z - wk.y * s4[q].w,
                                   ce.x * a1.y + ce.y * a1.x + wk.x * s4[q].w + wk.y * s4[q].z);
      }
    }
    // select layers: ONE fwd body (k=0,2 and k=3 qff via nL/scp), ONE adj body
    if (k == 1) {
#pragma unroll 1
      for (int L = 0; L < 2; ++L) run_layer<true>(a, sc + 40 * (1 - L), lane);
    } else {
      const float2* scp = (k == 3) ? &qscs[0] : sc;
      int nL = (k == 3) ? 1 : 2;
#pragma unroll 1
      for (int L = 0; L < nL; ++L) run_layer<false>(a, scp + 40 * L, lane);
    }
  }

  // ---- expvals: per-wave obs -> LDS -> block partial -> global sv atomics ----
  {
    float obs[30];
#pragma unroll
    for (int p = 0; p <= 9; ++p) {
      int i = 9 - p;
      float cr = 0.f, ci = 0.f, zz = 0.f;
      if (p < 4) {
        int m = 1 << p;
#pragma unroll
        for (int r0 = 0; r0 < 16; ++r0) {
          if (!(r0 & m)) {
            float2 A0 = a[r0], A1 = a[r0 | m];
            cr += A0.x * A1.x + A0.y * A1.y;
            ci += A0.x * A1.y - A0.y * A1.x;
            zz += (A0.x * A0.x + A0.y * A0.y) - (A1.x * A1.x + A1.y * A1.y);
          }
        }
      } else {
        int xm = 1 << (p - 4);
        bool up = (lane >> (p - 4)) & 1;
#pragma unroll
        for (int r = 0; r < 16; ++r) {
          float wx = __shfl_xor(a[r].x, xm, 64);
          float wy = __shfl_xor(a[r].y, xm, 64);
          float n2 = a[r].x * a[r].x + a[r].y * a[r].y;
          if (!up) {
            cr += a[r].x * wx + a[r].y * wy;
            ci += a[r].x * wy - a[r].y * wx;
            zz += n2;
          } else {
            zz -= n2;
          }
        }
      }
      obs[i] = 2.f * cr;
      obs[10 + i] = 2.f * ci;
      obs[20 + i] = zz;
    }
#pragma unroll
    for (int j = 0; j < 30; ++j) obs[j] = wave_sum(obs[j]);

    float* Rf = (float*)R;
    __syncthreads();                 // everyone done with R (mix 2 reads)
    if (lane == 0) {
#pragma unroll
      for (int j = 0; j < 30; ++j) Rf[w * 30 + j] = obs[j];
    }
    __syncthreads();
    if (w == 0) {
      if (lane < 30) {
        float v = Rf[0 * 30 + lane] + Rf[1 * 30 + lane] +
                  Rf[2 * 30 + lane] + Rf[3 * 30 + lane];
        atomicAdd(&sv[b * 30 + lane], v);
      }
      // last-arriving block of group b computes the output row
      int lastflag = 0;
      if (lane == 0) {
        unsigned old = __hip_atomic_fetch_add(&g_gb[b].done, 1u, __ATOMIC_ACQ_REL,
                                              __HIP_MEMORY_SCOPE_AGENT);
        lastflag = ((old & 3u) == 3u) ? 1 : 0;
      }
      lastflag = __shfl(lastflag, 0, 64);
      if (lastflag) {
        (void)__hip_atomic_load(&g_gb[b].done, __ATOMIC_ACQUIRE, __HIP_MEMORY_SCOPE_AGENT);
        if (lane < 8) {
          float acc = b_out[lane];
#pragma unroll
          for (int j = 0; j < 30; ++j) acc += W_out[lane * 30 + j] * sv[b * 30 + j];
          out[b * 8 + lane] = acc;
        }
      }
    }
  }
}

extern "C" void kernel_launch(void* const* d_in, const int* in_sizes, int n_in,
                              void* d_out, int out_size, void* d_ws, size_t ws_size,
                              hipStream_t stream) {
  const float* x     = (const float*)d_in[0];
  const float* W_fp  = (const float*)d_in[1];
  const float* b_fp  = (const float*)d_in[2];
  const float* prep  = (const float*)d_in[3];
  const float* sig   = (const float*)d_in[4];
  const float* qff   = (const float*)d_in[5];
  const float* W_out = (const float*)d_in[6];
  const float* b_out = (const float*)d_in[7];
  float* out = (float*)d_out;
  (void)in_sizes; (void)n_in; (void)out_size;

  // ws: part1 (512 KB) | part2 (512 KB) | sv (1920 B).  ws_size has been
  // >= 4 MB every round; this needs ~1.05 MB.
  char* ws = (char*)d_ws;
  const size_t SZ_PART = (size_t)64 * 512 * 16;   // 64 block-partials * 8 KB
  float4* part1 = (float4*)ws;
  float4* part2 = (float4*)(ws + SZ_PART);
  float*  sv    = (float*)(ws + 2 * SZ_PART);
  (void)ws_size;

  k_fused<<<dim3(64), dim3(256), 0, stream>>>(x, W_fp, b_fp, prep, sig, qff,
                                              W_out, b_out, out, part1, part2, sv);
}